// Round 10
// baseline (245.347 us; speedup 1.0000x reference)
//
#include <hip/hip_runtime.h>
#include <cstdint>
#include <cstddef>

typedef unsigned long long u64t;

// ---------------- numeric constants (fp64, 17 sig digits) ----------------
#define D_TAU1 0.36787944117144233   // exp(-1)
#define C_TAU1 2.7182818284590452    // e
#define D_TAU2 0.60653065971263342   // exp(-1/2)
#define C_TAU2 1.3591409142295226    // e/2
#define D_TAU4 0.77880078307140487   // exp(-1/4)
#define C_TAU4 0.67957045711476131   // e/4
#define DR1   0.36787944117144233
#define D32_1 1.2664165549094176e-14 // exp(-32)
#define CR1   -163.09690970754271    // -60e
#define DR2   0.60653065971263342
#define D32_2 1.1253517471925911e-7  // exp(-16)
#define CR2   -135.91409142295226    // -50e
#define DR3   0.77880078307140487
#define D32_3 3.3546262790251184e-4  // exp(-8)
#define CR3   -135.91409142295226    // -50e

// 4-state SLAYER refractory scan (known-good since R4-pass).
struct Spike { double Arf, Brf, Ad, Bd; unsigned long long hist; };

__device__ __forceinline__ double spike_step(Spike& st, double u, int t,
                                             double theta, double dr,
                                             double d32, double cr) {
  const double R = cr * (st.Brf - d32 * (st.Bd + 32.0 * st.Ad));
  const double v = u + R;
  const bool fire = (v >= theta);
  const double s = fire ? 1.0 : 0.0;
  st.Brf = dr * (st.Brf + st.Arf);
  st.Arf = dr * st.Arf + s;
  const double sd = (t >= 32) ? (double)((st.hist >> (t - 32)) & 1ull) : 0.0;
  st.Bd = dr * (st.Bd + st.Ad);
  st.Ad = dr * st.Ad + sd;
  if (fire) st.hist |= (1ull << t);
  return s;
}

__device__ __forceinline__ double bitd(unsigned m, int tt) {
  return (double)((m >> tt) & 1u);
}

// ---------------- geometry ----------------
// B=8, T=64. Workspace (~5 MB):
//   IM : (16 img, 4096 sites) u64 site-major input masks      0.5 MB
//   RW : (16 img, 64 y, 64 t) u64 time-major row-words        0.5 MB
//   S1 : (64 img = b*8+o, 4096 sites) u64 masks               2 MB
//   S2 : (16 img = b*2+o, 16384 sites) u64 masks              2 MB
//   ZP : 64 u64 zero page (OOB rows)                          512 B

// K1: input -> site masks (IM) and time-major row-words (RW) via LDS transpose.
__global__ __launch_bounds__(256) void k_masks(const float* __restrict__ x,
                                               u64t* __restrict__ im,
                                               u64t* __restrict__ rw,
                                               u64t* __restrict__ zp) {
  __shared__ u64t sh[256];
  const int idx = blockIdx.x * 256 + threadIdx.x;  // (bc,y,x), x fastest
  if (blockIdx.x == 0 && threadIdx.x < 64) zp[threadIdx.x] = 0ull;
  const float* xin = x + (size_t)idx * 64;
  u64t hist = 0ull;
  for (int t4 = 0; t4 < 16; ++t4) {
    const float4 v = reinterpret_cast<const float4*>(xin)[t4];
    if (v.x != 0.0f) hist |= 1ull << (t4 * 4 + 0);
    if (v.y != 0.0f) hist |= 1ull << (t4 * 4 + 1);
    if (v.z != 0.0f) hist |= 1ull << (t4 * 4 + 2);
    if (v.w != 0.0f) hist |= 1ull << (t4 * 4 + 3);
  }
  im[idx] = hist;
  sh[threadIdx.x] = hist;
  __syncthreads();
  const int base = threadIdx.x & ~63;   // this wave's 64 site masks (one row)
  const int t = threadIdx.x & 63;       // lane = time index
  u64t w = 0ull;
  for (int xx = 0; xx < 64; ++xx)
    w |= ((sh[base + xx] >> t) & 1ull) << xx;
  rw[idx] = w;   // rw[(bc,y)*64 + t], bit x = spike(x,t)
}

// ---- K2: spike1 = spike(psp1(conv5x5(input))) via row-words + LDS LUT ----
__global__ __launch_bounds__(256) void k_conv1_spike(
    const u64t* __restrict__ rw, const float* __restrict__ w1f,
    const u64t* __restrict__ zp, u64t* __restrict__ s1) {
  __shared__ double lut[5][1024];   // [conv row][ch1 bits<<5 | ch0 bits]
  const int o = blockIdx.y, b = blockIdx.z;
  const float* wo = w1f + o * 50;
  for (int e = threadIdx.x; e < 5 * 1024; e += 256) {   // blockDim flat 256: full cover
    const int r = e >> 10, pat = e & 1023;
    double s = 0.0;
#pragma unroll
    for (int j = 0; j < 5; ++j) {
      if (pat & (1 << j))       s += (double)wo[r * 5 + j];
      if (pat & (1 << (5 + j))) s += (double)wo[25 + r * 5 + j];
    }
    lut[r][pat] = s * C_TAU1;
  }
  __syncthreads();
  const int lane = threadIdx.x & 63;       // x
  const int wid = threadIdx.x >> 6;        // 0..3
  const int y = blockIdx.x * 4 + wid;      // 0..63
  // bits x-2..x+2 of word W: ((uint)(W>>sr) << sl) & 31, edge-safe
  const int sr = lane >= 2 ? lane - 2 : 0;
  const int sl = lane >= 2 ? 0 : 2 - lane;
  const u64t* p0[5];
  const u64t* p1[5];
#pragma unroll
  for (int r = 0; r < 5; ++r) {
    const int yr = y - 2 + r;
    const bool ok = (unsigned)yr < 64u;
    p0[r] = ok ? rw + ((size_t)(b * 2 + 0) * 4096 + yr * 64) : zp;
    p1[r] = ok ? rw + ((size_t)(b * 2 + 1) * 4096 + yr * 64) : zp;
  }
  double A = 0.0, B = 0.0;
  Spike st = {0, 0, 0, 0, 0ull};
  for (int t = 0; t < 64; ++t) {
    double d = 0.0;
#pragma unroll
    for (int r = 0; r < 5; ++r) {
      const u64t W0 = p0[r][t], W1 = p1[r][t];
      const unsigned q0 = (((unsigned)(W0 >> sr)) << sl) & 31u;
      const unsigned q1 = (((unsigned)(W1 >> sr)) << sl) & 31u;
      d += lut[r][q0 | (q1 << 5)];
    }
    B = D_TAU1 * (B + A);
    A = fma(D_TAU1, A, d);
    (void)spike_step(st, B, t, 30.0, DR1, D32_1, CR1);
  }
  s1[(size_t)(b * 8 + o) * 4096 + y * 64 + lane] = st.hist;
}

// ---- K3: spike2 = spike(deconv2x2(psp2(s1))), both o per thread, LUT ----
__global__ __launch_bounds__(256) void k_deconv_spike(
    const u64t* __restrict__ s1, const float* __restrict__ w2f,
    u64t* __restrict__ s2) {
  __shared__ double lut[4][2][256];   // [parity ii*2+jj][o][8-bit ch pattern]
  const int b = blockIdx.z;
  // R9 FIX: blockDim is (128,2) -> flatten tid, else half the LUT is never
  // written (uninitialized LDS zeroed the drives -> all-zero output, R6-R9).
  const int tid2 = threadIdx.y * 128 + threadIdx.x;
  for (int e = tid2; e < 2048; e += 256) {
    const int par = e >> 9, o = (e >> 8) & 1, pat = e & 255;
    const int ii = par >> 1, jj = par & 1;
    double s = 0.0;
#pragma unroll
    for (int c = 0; c < 8; ++c)
      if (pat & (1 << c)) s += (double)w2f[((c * 2 + o) * 2 + ii) * 2 + jj];
    lut[par][o][pat] = s * C_TAU2;
  }
  __syncthreads();
  const int X = threadIdx.x;                       // 0..127
  const int Y = blockIdx.x * 2 + threadIdx.y;      // 0..127
  const int xi = X >> 1, yi = Y >> 1;
  const int par = (Y & 1) * 2 + (X & 1);
  const unsigned* s132 = (const unsigned*)s1;
  double A0 = 0, B0 = 0, A1 = 0, B1 = 0;
  Spike st0 = {0, 0, 0, 0, 0ull}, st1 = {0, 0, 0, 0, 0ull};
#pragma unroll
  for (int half = 0; half < 2; ++half) {
    unsigned m[8];
#pragma unroll
    for (int c = 0; c < 8; ++c)
      m[c] = s132[2 * ((size_t)(b * 8 + c) * 4096 + yi * 64 + xi) + half];
    for (int tt = 0; tt < 32; ++tt) {
      const int t = half * 32 + tt;
      unsigned pat = 0;
#pragma unroll
      for (int c = 0; c < 8; ++c) pat |= ((m[c] >> tt) & 1u) << c;
      const double d0 = lut[par][0][pat];
      const double d1 = lut[par][1][pat];
      B0 = D_TAU2 * (B0 + A0); A0 = fma(D_TAU2, A0, d0);
      B1 = D_TAU2 * (B1 + A1); A1 = fma(D_TAU2, A1, d1);
      (void)spike_step(st0, B0, t, 50.0, DR2, D32_2, CR2);
      (void)spike_step(st1, B1, t, 50.0, DR2, D32_2, CR2);
    }
  }
  s2[(size_t)(b * 2 + 0) * 16384 + Y * 128 + X] = st0.hist;
  s2[(size_t)(b * 2 + 1) * 16384 + Y * 128 + X] = st1.hist;
}

// ---- K4: out = spike(conv3x3(psp3(s2)) + psp1(bilinear(input))), LUT ----
__global__ __launch_bounds__(256) void k_conv3_spike_out(
    const u64t* __restrict__ s2, const float* __restrict__ w3f,
    const u64t* __restrict__ im, float* __restrict__ out) {
  __shared__ double lut[2][2][512];   // [ch][o][9-bit 3x3 pattern]
  const int b = blockIdx.z;
  // R9 FIX: flatten (128,2) tid for full LUT coverage (see K3).
  const int tid2 = threadIdx.y * 128 + threadIdx.x;
  for (int e = tid2; e < 2048; e += 256) {
    const int ch = e >> 10, o = (e >> 9) & 1, pat = e & 511;
    double s = 0.0;
#pragma unroll
    for (int i = 0; i < 9; ++i)
      if (pat & (1 << i)) s += (double)w3f[o * 18 + ch * 9 + i];
    lut[ch][o][pat] = s * C_TAU4;
  }
  __syncthreads();
  const int X = threadIdx.x;                       // 0..127
  const int Y = blockIdx.x * 2 + threadIdx.y;      // 0..127
  // bilinear 2x taps (half-pixel, clamped), C_TAU1 folded in
  const int y0 = (Y - 1) >> 1, x0 = (X - 1) >> 1;
  const double wy1 = (Y & 1) ? 0.25 : 0.75, wy0 = 1.0 - wy1;
  const double wx1 = (X & 1) ? 0.25 : 0.75, wx0 = 1.0 - wx1;
  const int iy0 = max(y0, 0), iy1 = min(y0 + 1, 63);
  const int ix0 = max(x0, 0), ix1 = min(x0 + 1, 63);
  double ws[4];
  ws[0] = wy0 * wx0 * C_TAU1; ws[1] = wy0 * wx1 * C_TAU1;
  ws[2] = wy1 * wx0 * C_TAU1; ws[3] = wy1 * wx1 * C_TAU1;
  const size_t skidx[4] = {
    (size_t)iy0 * 64 + ix0, (size_t)iy0 * 64 + ix1,
    (size_t)iy1 * 64 + ix0, (size_t)iy1 * 64 + ix1 };
  const unsigned* s232 = (const unsigned*)s2;
  const unsigned* im32 = (const unsigned*)im;
  double Ac0 = 0, Bc0 = 0, Ac1 = 0, Bc1 = 0;
  double As0 = 0, Bs0 = 0, As1 = 0, Bs1 = 0;
  Spike st0 = {0, 0, 0, 0, 0ull}, st1 = {0, 0, 0, 0, 0ull};
#pragma unroll
  for (int half = 0; half < 2; ++half) {
    unsigned mc[18], ms0[4], ms1[4];
#pragma unroll
    for (int cc = 0; cc < 2; ++cc)
#pragma unroll
      for (int ky = 0; ky < 3; ++ky)
#pragma unroll
        for (int kx = 0; kx < 3; ++kx) {
          const int yn = Y - 1 + ky, xn = X - 1 + kx;
          const bool ok = ((unsigned)yn < 128u) & ((unsigned)xn < 128u);
          mc[cc * 9 + ky * 3 + kx] = ok ?
            s232[2 * ((size_t)(b * 2 + cc) * 16384 + yn * 128 + xn) + half] : 0u;
        }
#pragma unroll
    for (int i = 0; i < 4; ++i) {
      ms0[i] = im32[2 * ((size_t)(b * 2 + 0) * 4096 + skidx[i]) + half];
      ms1[i] = im32[2 * ((size_t)(b * 2 + 1) * 4096 + skidx[i]) + half];
    }
    for (int tt = 0; tt < 32; ++tt) {
      const int t = half * 32 + tt;
      unsigned p0 = 0, p1 = 0;
#pragma unroll
      for (int i = 0; i < 9; ++i) {
        p0 |= ((mc[i] >> tt) & 1u) << i;
        p1 |= ((mc[9 + i] >> tt) & 1u) << i;
      }
      const double dc0 = lut[0][0][p0] + lut[1][0][p1];
      const double dc1 = lut[0][1][p0] + lut[1][1][p1];
      double es0 = 0.0, es1 = 0.0;
#pragma unroll
      for (int i = 0; i < 4; ++i) {
        es0 = fma(ws[i], bitd(ms0[i], tt), es0);
        es1 = fma(ws[i], bitd(ms1[i], tt), es1);
      }
      Bc0 = D_TAU4 * (Bc0 + Ac0); Ac0 = fma(D_TAU4, Ac0, dc0);
      Bc1 = D_TAU4 * (Bc1 + Ac1); Ac1 = fma(D_TAU4, Ac1, dc1);
      Bs0 = D_TAU1 * (Bs0 + As0); As0 = fma(D_TAU1, As0, es0);
      Bs1 = D_TAU1 * (Bs1 + As1); As1 = fma(D_TAU1, As1, es1);
      (void)spike_step(st0, Bc0 + Bs0, t, 100.0, DR3, D32_3, CR3);
      (void)spike_step(st1, Bc1 + Bs1, t, 100.0, DR3, D32_3, CR3);
    }
  }
#pragma unroll
  for (int o = 0; o < 2; ++o) {
    const u64t h = o ? st1.hist : st0.hist;
    float* op = out + (((size_t)(b * 2 + o) * 128 + Y) * 128 + X) * 64;
#pragma unroll
    for (int t4 = 0; t4 < 16; ++t4) {
      float4 v;
      v.x = ((h >> (t4 * 4 + 0)) & 1ull) ? 1.0f : 0.0f;
      v.y = ((h >> (t4 * 4 + 1)) & 1ull) ? 1.0f : 0.0f;
      v.z = ((h >> (t4 * 4 + 2)) & 1ull) ? 1.0f : 0.0f;
      v.w = ((h >> (t4 * 4 + 3)) & 1ull) ? 1.0f : 0.0f;
      reinterpret_cast<float4*>(op)[t4] = v;
    }
  }
}

extern "C" void kernel_launch(void* const* d_in, const int* in_sizes, int n_in,
                              void* d_out, int out_size, void* d_ws, size_t ws_size,
                              hipStream_t stream) {
  const float* spikeIn = (const float*)d_in[0];   // (8,2,64,64,64) fp32
  const float* w1 = (const float*)d_in[1];        // (8,2,5,5)
  const float* w2 = (const float*)d_in[2];        // (8,2,2,2) = (in,out,i,j)
  const float* w3 = (const float*)d_in[3];        // (2,2,3,3)
  float* out = (float*)d_out;                     // (8,2,128,128,64) fp32

  u64t* IM = (u64t*)d_ws;                   // 0.5 MB
  u64t* RW = IM + (size_t)16 * 4096;        // 0.5 MB
  u64t* S1 = RW + (size_t)16 * 4096;        // 2 MB
  u64t* S2 = S1 + (size_t)64 * 4096;        // 2 MB
  u64t* ZP = S2 + (size_t)16 * 16384;       // 512 B

  k_masks<<<dim3(256), dim3(256), 0, stream>>>(spikeIn, IM, RW, ZP);
  k_conv1_spike<<<dim3(16, 8, 8), dim3(256), 0, stream>>>(RW, w1, ZP, S1);
  k_deconv_spike<<<dim3(64, 1, 8), dim3(128, 2), 0, stream>>>(S1, w2, S2);
  k_conv3_spike_out<<<dim3(64, 1, 8), dim3(128, 2), 0, stream>>>(S2, w3, IM, out);
}